// Round 1
// baseline (1017.651 us; speedup 1.0000x reference)
//
#include <hip/hip_runtime.h>
#include <stdint.h>

#define B_SZ   4096
#define IN_SZ  1024
#define NE     8
#define NC     1000
#define HIDE   16384   // HID*E
#define OUTE   1024    // OUT per expert
#define GEPS   1e-6f

typedef __attribute__((ext_vector_type(8))) short short8;
typedef __attribute__((ext_vector_type(4))) float floatx4;

__device__ __forceinline__ unsigned short f2bf(float f) {
    unsigned u = __float_as_uint(f);
    u += 0x7fffu + ((u >> 16) & 1u);
    return (unsigned short)(u >> 16);
}
__device__ __forceinline__ float bf2f(unsigned short h) {
    return __uint_as_float(((unsigned)h) << 16);
}

__device__ __forceinline__ void async16(const void* g, void* l) {
    __builtin_amdgcn_global_load_lds(
        (const __attribute__((address_space(1))) void*)g,
        (__attribute__((address_space(3))) void*)l, 16, 0, 0);
}

// ---------------- conversion fp32 -> bf16 (vectorized, grid-stride) -------------
__global__ __launch_bounds__(256) void k_cvt(const float* __restrict__ src,
                                             unsigned short* __restrict__ dst, int n) {
    int i = (blockIdx.x * 256 + threadIdx.x) * 4;
    int stride = gridDim.x * 256 * 4;
    for (; i < n; i += stride) {
        float4 v = *(const float4*)(src + i);
        ushort4 o;
        o.x = f2bf(v.x); o.y = f2bf(v.y); o.z = f2bf(v.z); o.w = f2bf(v.w);
        *(ushort4*)(dst + i) = o;
    }
}

// ---------------- gating: logits + row norm (fp32 exact path) -------------------
__global__ __launch_bounds__(256) void k_gate(const float* __restrict__ x,
                                              const float* __restrict__ Wg,
                                              const float* __restrict__ bg,
                                              float* __restrict__ logits,
                                              float* __restrict__ Gx) {
    int wid = threadIdx.x >> 6, lane = threadIdx.x & 63;
    int b = blockIdx.x * 4 + wid;
    const float* xr = x + (size_t)b * IN_SZ;
    float xv[16];
#pragma unroll
    for (int t = 0; t < 16; ++t) xv[t] = xr[lane + 64 * t];
    float lg[NE];
#pragma unroll
    for (int e = 0; e < NE; ++e) {
        const float* wr = Wg + e * IN_SZ;
        float s = 0.f;
#pragma unroll
        for (int t = 0; t < 16; ++t) s += xv[t] * wr[lane + 64 * t];
#pragma unroll
        for (int m = 32; m >= 1; m >>= 1) s += __shfl_xor(s, m, 64);
        lg[e] = s + bg[e];
    }
    if (lane == 0) {
        float ss = 0.f;
#pragma unroll
        for (int e = 0; e < NE; ++e) { logits[b * NE + e] = lg[e]; ss += lg[e] * lg[e]; }
        Gx[b] = sqrtf(ss);
    }
}

// deterministic batch-sum of Gx
__global__ __launch_bounds__(1024) void k_gsum(const float* __restrict__ Gx, float* __restrict__ gsum) {
    __shared__ float sm[1024];
    int t = threadIdx.x;
    sm[t] = Gx[t] + Gx[t + 1024] + Gx[t + 2048] + Gx[t + 3072];
    __syncthreads();
    for (int m = 512; m >= 1; m >>= 1) {
        if (t < m) sm[t] += sm[t + m];
        __syncthreads();
    }
    if (t == 0) gsum[0] = sm[0];
}

__global__ void k_zeroctrl(int* ctrl) {
    if (threadIdx.x < 24) ctrl[threadIdx.x] = 0;   // counts[8] + cursors[8] + spare
}

// GRN + softmax + top2 (ties -> lower index, matching lax.top_k)
__global__ __launch_bounds__(256) void k_topk(const float* __restrict__ logits,
                                              const float* __restrict__ Gx,
                                              const float* __restrict__ gsum,
                                              const float* __restrict__ gamma,
                                              const float* __restrict__ beta,
                                              int* __restrict__ tidx, float* __restrict__ tp,
                                              int* __restrict__ counts) {
    int b = blockIdx.x * 256 + threadIdx.x;
    float nx = Gx[b] / (gsum[0] * (1.0f / (float)B_SZ) + GEPS);
    float l[NE];
    float mx = -1e30f;
#pragma unroll
    for (int e = 0; e < NE; ++e) {
        l[e] = gamma[e] * (logits[b * NE + e] * nx) + beta[e];
        mx = fmaxf(mx, l[e]);
    }
    float se = 0.f;
#pragma unroll
    for (int e = 0; e < NE; ++e) { l[e] = expf(l[e] - mx); se += l[e]; }
    float inv = 1.f / se;
    int i0 = 0; float p0 = l[0];
#pragma unroll
    for (int e = 1; e < NE; ++e) if (l[e] > p0) { p0 = l[e]; i0 = e; }
    int i1 = -1; float p1 = -1.f;
#pragma unroll
    for (int e = 0; e < NE; ++e) if (e != i0 && l[e] > p1) { p1 = l[e]; i1 = e; }
    tidx[b * 2 + 0] = i0; tidx[b * 2 + 1] = i1;
    tp[b * 2 + 0] = p0 * inv; tp[b * 2 + 1] = p1 * inv;
    atomicAdd(&counts[i0], 1);
    atomicAdd(&counts[i1], 1);
}

__global__ void k_offsets(const int* __restrict__ counts, int* __restrict__ offs) {
    if (threadIdx.x == 0) {
        int a = 0;
        for (int e = 0; e < NE; ++e) { offs[e] = a; a += counts[e]; }
    }
}

__global__ __launch_bounds__(256) void k_fill(const int* __restrict__ tidx, const float* __restrict__ tp,
                                              const int* __restrict__ offs, int* __restrict__ cursors,
                                              int* __restrict__ rowsw, float* __restrict__ probsw) {
    int b = blockIdx.x * 256 + threadIdx.x;
#pragma unroll
    for (int k = 0; k < 2; ++k) {
        int e = tidx[b * 2 + k];
        int pos = atomicAdd(&cursors[e], 1);
        int at = offs[e] + pos;
        rowsw[at] = b * 2 + k;       // encodes gather row (>>1) and dest slot
        probsw[at] = tp[b * 2 + k];
    }
}

// ---------------- shared m97-style 128x128xBK32 MFMA core -----------------------
__device__ __forceinline__ void gemm_core(const unsigned short* sa0, const unsigned short* sa1,
                                          const unsigned short* sb0, const unsigned short* sb1,
                                          short* sA, short* sB, int nkt, int wid, int lane,
                                          floatx4 acc[4][4]) {
    short* ldsA0 = sA + (wid * 2 + 0) * 512;
    short* ldsA1 = sA + (wid * 2 + 1) * 512;
    short* ldsB0 = sB + (wid * 2 + 0) * 512;
    short* ldsB1 = sB + (wid * 2 + 1) * 512;
    const int wm = wid >> 1, wn = wid & 1;
    int aoff[4], boff[4];
#pragma unroll
    for (int i = 0; i < 4; ++i) {
        aoff[i] = (wm * 64 + i * 16 + (lane & 15)) * 32 + (lane >> 4) * 8;
        boff[i] = (wn * 64 + i * 16 + (lane & 15)) * 32 + (lane >> 4) * 8;
    }
    for (int kt = 0; kt < nkt; ++kt) {
        __syncthreads();                 // previous compute done before overwrite
        async16(sa0, ldsA0);
        async16(sa1, ldsA1);
        async16(sb0, ldsB0);
        async16(sb1, ldsB1);
        sa0 += 32; sa1 += 32; sb0 += 32; sb1 += 32;
        __syncthreads();                 // vmcnt(0) drained by barrier semantics
        short8 av[4], bv[4];
#pragma unroll
        for (int i = 0; i < 4; ++i) av[i] = *(const short8*)(sA + aoff[i]);
#pragma unroll
        for (int j = 0; j < 4; ++j) bv[j] = *(const short8*)(sB + boff[j]);
#pragma unroll
        for (int i = 0; i < 4; ++i)
#pragma unroll
            for (int j = 0; j < 4; ++j)
                acc[i][j] = __builtin_amdgcn_mfma_f32_16x16x32_bf16(av[i], bv[j], acc[i][j], 0, 0, 0);
    }
}

// GEMM1: h = relu(x @ W1^T + b1)   [4096,1024]x[16384,1024] -> [4096,16384] bf16
__global__ __launch_bounds__(256) void k_gemm_h(const unsigned short* __restrict__ xb,
                                                const unsigned short* __restrict__ w1b,
                                                const float* __restrict__ b1,
                                                unsigned short* __restrict__ h) {
    __shared__ __align__(16) short sA[128 * 32];
    __shared__ __align__(16) short sB[128 * 32];
    const int lane = threadIdx.x & 63, wid = threadIdx.x >> 6;
    const int mt = blockIdx.x & 31, nt = blockIdx.x >> 5;
    const int m0 = mt * 128, n0 = nt * 128;
    const int t0row = (wid * 2 + 0) * 16 + (lane >> 2);
    const int t1row = (wid * 2 + 1) * 16 + (lane >> 2);
    const int kb = (lane & 3) * 8;
    const unsigned short* sa0 = xb + (size_t)(m0 + t0row) * IN_SZ + kb;
    const unsigned short* sa1 = xb + (size_t)(m0 + t1row) * IN_SZ + kb;
    const unsigned short* sb0 = w1b + (size_t)(n0 + t0row) * IN_SZ + kb;
    const unsigned short* sb1 = w1b + (size_t)(n0 + t1row) * IN_SZ + kb;
    floatx4 acc[4][4] = {};
    gemm_core(sa0, sa1, sb0, sb1, sA, sB, IN_SZ / 32, wid, lane, acc);
    const int wm = wid >> 1, wn = wid & 1;
#pragma unroll
    for (int i = 0; i < 4; ++i)
#pragma unroll
        for (int j = 0; j < 4; ++j)
#pragma unroll
            for (int r = 0; r < 4; ++r) {
                int row = m0 + wm * 64 + i * 16 + (lane >> 4) * 4 + r;
                int col = n0 + wn * 64 + j * 16 + (lane & 15);
                float v = acc[i][j][r] + b1[col];
                h[(size_t)row * HIDE + col] = f2bf(fmaxf(v, 0.f));
            }
}

// GEMM2 (grouped): per expert group, gathered-A h rows x W2 slice -> scaled slot outputs
__global__ __launch_bounds__(256) void k_gemm_moe(const unsigned short* __restrict__ h,
                                                  const unsigned short* __restrict__ w2b,
                                                  const float* __restrict__ b2,
                                                  const int* __restrict__ counts,
                                                  const int* __restrict__ offs,
                                                  const int* __restrict__ rowsw,
                                                  const float* __restrict__ probsw,
                                                  unsigned short* __restrict__ slotbuf) {
    const int bid = blockIdx.x;
    const int e = bid >> 8;
    const int rem = bid & 255;
    const int mt = rem >> 3, nt = rem & 7;
    const int gn = counts[e];
    if (mt * 128 >= gn) return;
    const int gbase = offs[e];
    __shared__ __align__(16) short sA[128 * 32];
    __shared__ __align__(16) short sB[128 * 32];
    const int lane = threadIdx.x & 63, wid = threadIdx.x >> 6;
    const int t0row = (wid * 2 + 0) * 16 + (lane >> 2);
    const int t1row = (wid * 2 + 1) * 16 + (lane >> 2);
    const int kb = (lane & 3) * 8;
    int g0 = mt * 128 + t0row; if (g0 > gn - 1) g0 = gn - 1;
    int g1 = mt * 128 + t1row; if (g1 > gn - 1) g1 = gn - 1;
    const int rv0 = rowsw[gbase + g0] >> 1;
    const int rv1 = rowsw[gbase + g1] >> 1;
    const int n0 = nt * 128;
    const unsigned short* sa0 = h + (size_t)rv0 * HIDE + kb;
    const unsigned short* sa1 = h + (size_t)rv1 * HIDE + kb;
    const unsigned short* sb0 = w2b + (size_t)(e * OUTE + n0 + t0row) * HIDE + kb;
    const unsigned short* sb1 = w2b + (size_t)(e * OUTE + n0 + t1row) * HIDE + kb;
    floatx4 acc[4][4] = {};
    gemm_core(sa0, sa1, sb0, sb1, sA, sB, HIDE / 32, wid, lane, acc);
    const int wm = wid >> 1, wn = wid & 1;
#pragma unroll
    for (int i = 0; i < 4; ++i)
#pragma unroll
        for (int j = 0; j < 4; ++j)
#pragma unroll
            for (int r = 0; r < 4; ++r) {
                int lr = mt * 128 + wm * 64 + i * 16 + (lane >> 4) * 4 + r;
                if (lr < gn) {
                    int at = gbase + lr;
                    int dest = rowsw[at];
                    float p = probsw[at];
                    int col = n0 + wn * 64 + j * 16 + (lane & 15);
                    float v = (acc[i][j][r] + b2[e * OUTE + col]) * p;
                    slotbuf[(size_t)dest * OUTE + col] = f2bf(v);
                }
            }
}

// combine the two slots per row -> ymix bf16
__global__ __launch_bounds__(256) void k_combine(const unsigned short* __restrict__ slotbuf,
                                                 unsigned short* __restrict__ ymix) {
    int i = blockIdx.x * 256 + threadIdx.x;    // 524288 units of 8
    int b = i >> 7;
    int d = (i & 127) * 8;
    short8 s0 = *(const short8*)(slotbuf + (size_t)(b * 2 + 0) * OUTE + d);
    short8 s1 = *(const short8*)(slotbuf + (size_t)(b * 2 + 1) * OUTE + d);
    short8 o;
#pragma unroll
    for (int t = 0; t < 8; ++t)
        o[t] = (short)f2bf(bf2f((unsigned short)s0[t]) + bf2f((unsigned short)s1[t]));
    *(short8*)(ymix + (size_t)b * OUTE + d) = o;
}

// GEMM3: out = ymix @ Wc^T + bc  [4096,1024]x[1000,1024] -> [4096,1000] fp32
__global__ __launch_bounds__(256) void k_gemm_out(const unsigned short* __restrict__ ymix,
                                                  const unsigned short* __restrict__ wcb,
                                                  const float* __restrict__ bc,
                                                  float* __restrict__ out) {
    const int mt = blockIdx.x >> 3, nt = blockIdx.x & 7;
    const int m0 = mt * 128, n0 = nt * 128;
    __shared__ __align__(16) short sA[128 * 32];
    __shared__ __align__(16) short sB[128 * 32];
    const int lane = threadIdx.x & 63, wid = threadIdx.x >> 6;
    const int t0row = (wid * 2 + 0) * 16 + (lane >> 2);
    const int t1row = (wid * 2 + 1) * 16 + (lane >> 2);
    const int kb = (lane & 3) * 8;
    int br0 = n0 + t0row; if (br0 > NC - 1) br0 = NC - 1;
    int br1 = n0 + t1row; if (br1 > NC - 1) br1 = NC - 1;
    const unsigned short* sa0 = ymix + (size_t)(m0 + t0row) * IN_SZ + kb;
    const unsigned short* sa1 = ymix + (size_t)(m0 + t1row) * IN_SZ + kb;
    const unsigned short* sb0 = wcb + (size_t)br0 * IN_SZ + kb;
    const unsigned short* sb1 = wcb + (size_t)br1 * IN_SZ + kb;
    floatx4 acc[4][4] = {};
    gemm_core(sa0, sa1, sb0, sb1, sA, sB, IN_SZ / 32, wid, lane, acc);
    const int wm = wid >> 1, wn = wid & 1;
#pragma unroll
    for (int i = 0; i < 4; ++i)
#pragma unroll
        for (int j = 0; j < 4; ++j)
#pragma unroll
            for (int r = 0; r < 4; ++r) {
                int row = m0 + wm * 64 + i * 16 + (lane >> 4) * 4 + r;
                int col = n0 + wn * 64 + j * 16 + (lane & 15);
                if (col < NC)
                    out[(size_t)row * NC + col] = acc[i][j][r] + bc[col];
            }
}

extern "C" void kernel_launch(void* const* d_in, const int* in_sizes, int n_in,
                              void* d_out, int out_size, void* d_ws, size_t ws_size,
                              hipStream_t stream) {
    const float* x     = (const float*)d_in[0];
    const float* Wg    = (const float*)d_in[1];
    const float* bg    = (const float*)d_in[2];
    const float* gamma = (const float*)d_in[3];
    const float* beta  = (const float*)d_in[4];
    const float* W1    = (const float*)d_in[5];
    const float* b1    = (const float*)d_in[6];
    const float* W2    = (const float*)d_in[7];
    const float* b2    = (const float*)d_in[8];
    const float* Wc    = (const float*)d_in[9];
    const float* bc    = (const float*)d_in[10];
    float* out = (float*)d_out;

    // workspace carving (all 256B aligned)
    char* ws = (char*)d_ws;
    size_t o = 0;
    auto carve = [&](size_t bytes) { char* p = ws + o; o += (bytes + 255) & ~(size_t)255; return p; };
    unsigned short* xb   = (unsigned short*)carve((size_t)B_SZ * IN_SZ * 2);
    unsigned short* w1b  = (unsigned short*)carve((size_t)HIDE * IN_SZ * 2);
    unsigned short* w2b  = (unsigned short*)carve((size_t)NE * OUTE * HIDE * 2);
    unsigned short* wcb  = (unsigned short*)carve((size_t)NC * IN_SZ * 2);
    unsigned short* h    = (unsigned short*)carve((size_t)B_SZ * HIDE * 2);
    unsigned short* slot = (unsigned short*)carve((size_t)B_SZ * 2 * OUTE * 2);
    unsigned short* ymix = (unsigned short*)carve((size_t)B_SZ * OUTE * 2);
    float* logits = (float*)carve((size_t)B_SZ * NE * 4);
    float* Gx     = (float*)carve((size_t)B_SZ * 4);
    int*   tidx   = (int*)carve((size_t)B_SZ * 2 * 4);
    float* tp     = (float*)carve((size_t)B_SZ * 2 * 4);
    int*   rowsw  = (int*)carve((size_t)B_SZ * 2 * 4);
    float* probsw = (float*)carve((size_t)B_SZ * 2 * 4);
    int*   ctrl   = (int*)carve(256);
    int* counts  = ctrl;
    int* cursors = ctrl + 8;
    int* offs    = ctrl + 16;
    float* gsum  = (float*)(ctrl + 24);

    // conversions
    k_cvt<<<2048, 256, 0, stream>>>(x,  xb,  B_SZ * IN_SZ);
    k_cvt<<<2048, 256, 0, stream>>>(W1, w1b, HIDE * IN_SZ);
    k_cvt<<<2048, 256, 0, stream>>>(W2, w2b, NE * OUTE * HIDE);
    k_cvt<<<2048, 256, 0, stream>>>(Wc, wcb, NC * IN_SZ);

    // gating / routing
    k_gate<<<B_SZ / 4, 256, 0, stream>>>(x, Wg, bg, logits, Gx);
    k_gsum<<<1, 1024, 0, stream>>>(Gx, gsum);
    k_zeroctrl<<<1, 64, 0, stream>>>(ctrl);
    k_topk<<<B_SZ / 256, 256, 0, stream>>>(logits, Gx, gsum, gamma, beta, tidx, tp, counts);
    k_offsets<<<1, 64, 0, stream>>>(counts, offs);
    k_fill<<<B_SZ / 256, 256, 0, stream>>>(tidx, tp, offs, cursors, rowsw, probsw);

    // GEMMs
    k_gemm_h<<<32 * (HIDE / 128), 256, 0, stream>>>(xb, w1b, b1, h);
    k_gemm_moe<<<NE * 32 * 8, 256, 0, stream>>>(h, w2b, b2, counts, offs, rowsw, probsw, slot);
    k_combine<<<(B_SZ * OUTE / 8) / 256, 256, 0, stream>>>(slot, ymix);
    k_gemm_out<<<32 * 8, 256, 0, stream>>>(ymix, wcb, bc, out);
}